// Round 7
// baseline (21097.031 us; speedup 1.0000x reference)
//
#include <hip/hip_runtime.h>
#include <math.h>

#define BB 128
#define TT 1024
#define FF 64
#define HH 512
#define G4 2048            // 4*HH gate rows
#define NI 8               // batch groups (independent)
#define NJ 16              // hidden slices per group (32 units each)
#define BT 16
#define NBLK 128
#define LDK 520            // padded LDS row (u16): 1040B stride

typedef float f32x4 __attribute__((ext_vector_type(4)));
typedef short s16x8 __attribute__((ext_vector_type(8)));
typedef unsigned short u16;
typedef unsigned int u32;
typedef unsigned long long u64;

// ---- canonical fp32 inputs ----
__device__ float g_ts[BB * TT * FF];
__device__ float g_wihe[G4 * FF];
__device__ float g_whhe[G4 * HH];
__device__ float g_bihe[G4], g_bhhe[G4], g_bihd[G4], g_bhhd[G4];
__device__ float g_wihd[G4 * FF];
__device__ float g_whhd[G4 * HH];
__device__ float g_wout[FF * HH];
__device__ float g_bout[FF];
// ---- precomputed fused decoder weights ----
__device__ float g_weff[G4 * HH];
__device__ float g_beff[G4];
// ---- inter-block state (agent-scope atomics only) ----
__device__ __align__(16) u32 g_hpak[2 * BB * HH];       // [parity][BB][HH] (hi | lo<<16)
__device__ float g_part[4 * NI * NJ * BT * FF];         // depth-4 ring
__device__ int   g_isbf16;

__device__ __forceinline__ float bf2f(u16 u) {
  union { unsigned u; float f; } x; x.u = ((unsigned)u) << 16; return x.f;
}
__device__ __forceinline__ u16 f2bf(float f) {
  union { float f; unsigned u; } x; x.f = f;
  unsigned r = x.u + 0x7fffu + ((x.u >> 16) & 1u);
  return (u16)(r >> 16);
}

__global__ void sniff_kernel(const void* wout) {
  __shared__ int cnt[64];
  int t = threadIdx.x;
  const unsigned* d = (const unsigned*)wout;
  int c = 0;
  for (int k = t; k < 1024; k += 64) {
    unsigned b = (d[k] >> 8) & 0x7fu;
    c += (b >= 0x30u && b <= 0x3eu) ? 1 : 0;
  }
  cnt[t] = c;
  __syncthreads();
  if (t == 0) {
    int s = 0;
    for (int k = 0; k < 64; ++k) s += cnt[k];
    g_isbf16 = (s > 512) ? 1 : 0;
  }
}

__global__ void convert_kernel(const void* __restrict__ src, int which, int n) {
  int idx = blockIdx.x * 256 + threadIdx.x;
  if (idx >= n) return;
  float v;
  if (g_isbf16) v = bf2f(((const u16*)src)[idx]);
  else          v = ((const float*)src)[idx];
  float* dst;
  switch (which) {
    case 0: dst = g_ts;   break;
    case 1: dst = g_wihe; break;
    case 2: dst = g_whhe; break;
    case 3: dst = g_bihe; break;
    case 4: dst = g_bhhe; break;
    case 5: dst = g_wihd; break;
    case 6: dst = g_whhd; break;
    case 7: dst = g_bihd; break;
    case 8: dst = g_bhhd; break;
    case 9: dst = g_wout; break;
    default: dst = g_bout; break;
  }
  dst[idx] = v;
}

__global__ void prep_kernel() {
  int idx = blockIdx.x * 256 + threadIdx.x;
  int r = idx >> 9, c = idx & 511;
  float acc = g_whhd[idx];
  const float* wr = &g_wihd[r * FF];
  for (int f = 0; f < FF; ++f) acc += wr[f] * g_wout[f * HH + c];
  g_weff[idx] = acc;
  if (idx < G4) {
    float b = g_bihd[idx] + g_bhhd[idx];
    for (int f = 0; f < FF; ++f) b += g_wihd[idx * FF + f] * g_bout[f];
    g_beff[idx] = b;
  }
}

#define MFMA __builtin_amdgcn_mfma_f32_16x16x32_bf16
#define A_LD(p)  __hip_atomic_load((p), __ATOMIC_RELAXED, __HIP_MEMORY_SCOPE_AGENT)
#define A_ST(p, v) __hip_atomic_store((p), (v), __ATOMIC_RELAXED, __HIP_MEMORY_SCOPE_AGENT)

__global__ __launch_bounds__(256, 1) void lstm_persist(unsigned* __restrict__ bar,
                                                       void* __restrict__ outv) {
  __shared__ u16 sH[32 * LDK];      // rows 0-15: h_hi, rows 16-31: h_lo
  __shared__ float sXg[4][16][32];  // gate exchange i/f/g/o
  __shared__ float sHn[16][32];     // h_new f32 for y-partials
  __shared__ float sWo[64][32];     // w_out[:, 32j:32j+32]

  const int tid = threadIdx.x, bid = blockIdx.x;
  const int i = bid & 7, j = bid >> 3;      // group i ~ XCD-affine, j 0..15
  const int wv = tid >> 6, lane = tid & 63;
  const int ln15 = lane & 15, lq = lane >> 4;
  const int m_t = tid >> 4, n_t = tid & 15;
  const bool isbf = (g_isbf16 != 0);
  unsigned* flags = bar + i * 256;          // 16 flags per group, each on own 64B line
  unsigned* myflag = flags + j * 16;

  const int gr0 = (wv << 9) + (j << 5) + ln15;        // ntile 0 gate row
  const int gr1 = gr0 + 16;                           // ntile 1 gate row

  // ---- hidden weights -> registers (hi/lo bf16), encoder phase ----
  s16x8 wh0[16], wl0[16], wh1[16], wl1[16];
#pragma unroll
  for (int kt = 0; kt < 16; ++kt) {
    const float* p0 = &g_whhe[(size_t)gr0 * HH + kt * 32 + lq * 8];
    const float* p1 = &g_whhe[(size_t)gr1 * HH + kt * 32 + lq * 8];
#pragma unroll
    for (int q = 0; q < 8; ++q) {
      float w = p0[q]; u16 hi = f2bf(w);
      wh0[kt][q] = (short)hi; wl0[kt][q] = (short)f2bf(w - bf2f(hi));
      w = p1[q]; hi = f2bf(w);
      wh1[kt][q] = (short)hi; wl1[kt][q] = (short)f2bf(w - bf2f(hi));
    }
  }
  s16x8 bxh[2][2], bxl[2][2];   // encoder x-weight fragments [ntile][k-half]
#pragma unroll
  for (int nt = 0; nt < 2; ++nt) {
    const float* p0 = &g_wihe[(size_t)(nt ? gr1 : gr0) * FF + lq * 8];
#pragma unroll
    for (int q = 0; q < 8; ++q) {
      float w0 = p0[q], w1 = p0[32 + q];
      u16 h0 = f2bf(w0), h1 = f2bf(w1);
      bxh[nt][0][q] = (short)h0; bxl[nt][0][q] = (short)f2bf(w0 - bf2f(h0));
      bxh[nt][1][q] = (short)h1; bxl[nt][1][q] = (short)f2bf(w1 - bf2f(h1));
    }
  }
  for (int idx = tid; idx < 64 * 32; idx += 256) {
    int f = idx >> 5, n = idx & 31;
    sWo[f][n] = g_wout[f * HH + (j << 5) + n];
  }
  float bias0 = g_bihe[gr0] + g_bhhe[gr0];
  float bias1 = g_bihe[gr1] + g_bhhe[gr1];

  // zero h parity 0 (packed)
  A_ST(&g_hpak[(size_t)(0 * BB + i * BT + m_t) * HH + (j << 5) + n_t], 0u);
  A_ST(&g_hpak[(size_t)(0 * BB + i * BT + m_t) * HH + (j << 5) + 16 + n_t], 0u);

  // publish init: drain, relaxed flag (manual drain orders it), wait group
  asm volatile("s_waitcnt vmcnt(0)" ::: "memory");
  __syncthreads();
  if (tid == 0) A_ST(myflag, 1u);
  if (tid < 64) {
    unsigned* fp = flags + (lane & 15) * 16;
    while (true) {
      unsigned v = A_LD(fp);
      if (__ballot(v >= 1u) == ~0ull) break;
      __builtin_amdgcn_s_sleep(1);
    }
  }
  asm volatile("" ::: "memory");
  __syncthreads();

  float c0 = 0.f, c1 = 0.f;
  const int arow = ln15 * LDK;
  const int koff = lq * 8;

  for (int g = 0; g <= 2048; ++g) {
    const int cur = g & 1, nxt = cur ^ 1;
    const bool run = (g < 2048);
    float hn0 = 0.f, hn1 = 0.f;

    if (run) {
      const bool enc = (g < 1024);
      s16x8 xh0 = {}, xl0 = {}, xh1 = {}, xl1 = {};
      if (enc) {
        const float* xp = &g_ts[((size_t)(i * BT + ln15) * TT + g) * FF + lq * 8];
#pragma unroll
        for (int q = 0; q < 8; ++q) {
          float x0 = xp[q], x1 = xp[32 + q];
          u16 h0 = f2bf(x0), h1 = f2bf(x1);
          xh0[q] = (short)h0; xl0[q] = (short)f2bf(x0 - bf2f(h0));
          xh1[q] = (short)h1; xl1[q] = (short)f2bf(x1 - bf2f(h1));
        }
      }
      // stage packed h -> unpack to hi/lo LDS planes (v_perm)
      {
        int r = tid >> 4, cb = (tid & 15) * 32;   // batch row, unit offset
        const u64* ph = (const u64*)(g_hpak + ((size_t)(cur * BB + i * BT + r) * HH) + cb);
        u64 q[16];
#pragma unroll
        for (int k = 0; k < 16; ++k) q[k] = A_LD(ph + k);
        union Du { u32 d[4]; s16x8 v; };
#pragma unroll
        for (int k = 0; k < 4; ++k) {   // 8 units per chunk
          u32 w0 = (u32)q[4 * k + 0], w1 = (u32)(q[4 * k + 0] >> 32);
          u32 w2 = (u32)q[4 * k + 1], w3 = (u32)(q[4 * k + 1] >> 32);
          u32 w4 = (u32)q[4 * k + 2], w5 = (u32)(q[4 * k + 2] >> 32);
          u32 w6 = (u32)q[4 * k + 3], w7 = (u32)(q[4 * k + 3] >> 32);
          Du hi, lo;
          hi.d[0] = __builtin_amdgcn_perm(w1, w0, 0x05040100u);
          hi.d[1] = __builtin_amdgcn_perm(w3, w2, 0x05040100u);
          hi.d[2] = __builtin_amdgcn_perm(w5, w4, 0x05040100u);
          hi.d[3] = __builtin_amdgcn_perm(w7, w6, 0x05040100u);
          lo.d[0] = __builtin_amdgcn_perm(w1, w0, 0x07060302u);
          lo.d[1] = __builtin_amdgcn_perm(w3, w2, 0x07060302u);
          lo.d[2] = __builtin_amdgcn_perm(w5, w4, 0x07060302u);
          lo.d[3] = __builtin_amdgcn_perm(w7, w6, 0x07060302u);
          *(s16x8*)&sH[r * LDK + cb + 8 * k] = hi.v;
          *(s16x8*)&sH[(16 + r) * LDK + cb + 8 * k] = lo.v;
        }
      }
      __syncthreads();

      f32x4 a00 = {bias0, bias0, bias0, bias0};
      f32x4 a10 = {bias1, bias1, bias1, bias1};
      f32x4 a01 = {0.f, 0.f, 0.f, 0.f}, a02 = a01, a11 = a01, a12 = a01;
#pragma unroll
      for (int kt = 0; kt < 16; ++kt) {
        s16x8 ah = *(s16x8*)&sH[arow + kt * 32 + koff];
        s16x8 al = *(s16x8*)&sH[16 * LDK + arow + kt * 32 + koff];
        a00 = MFMA(ah, wh0[kt], a00, 0, 0, 0);
        a01 = MFMA(al, wh0[kt], a01, 0, 0, 0);
        a02 = MFMA(ah, wl0[kt], a02, 0, 0, 0);
        a10 = MFMA(ah, wh1[kt], a10, 0, 0, 0);
        a11 = MFMA(al, wh1[kt], a11, 0, 0, 0);
        a12 = MFMA(ah, wl1[kt], a12, 0, 0, 0);
      }
      if (enc) {
        a00 = MFMA(xh0, bxh[0][0], a00, 0, 0, 0);
        a00 = MFMA(xh1, bxh[0][1], a00, 0, 0, 0);
        a01 = MFMA(xl0, bxh[0][0], a01, 0, 0, 0);
        a01 = MFMA(xl1, bxh[0][1], a01, 0, 0, 0);
        a02 = MFMA(xh0, bxl[0][0], a02, 0, 0, 0);
        a02 = MFMA(xh1, bxl[0][1], a02, 0, 0, 0);
        a10 = MFMA(xh0, bxh[1][0], a10, 0, 0, 0);
        a10 = MFMA(xh1, bxh[1][1], a10, 0, 0, 0);
        a11 = MFMA(xl0, bxh[1][0], a11, 0, 0, 0);
        a11 = MFMA(xl1, bxh[1][1], a11, 0, 0, 0);
        a12 = MFMA(xh0, bxl[1][0], a12, 0, 0, 0);
        a12 = MFMA(xh1, bxl[1][1], a12, 0, 0, 0);
      }
#pragma unroll
      for (int r = 0; r < 4; ++r) {
        sXg[wv][lq * 4 + r][ln15]      = a00[r] + a01[r] + a02[r];
        sXg[wv][lq * 4 + r][16 + ln15] = a10[r] + a11[r] + a12[r];
      }
      __syncthreads();

      // elementwise: each thread handles units n_t and n_t+16 for batch row m_t
      {
        float gi = sXg[0][m_t][n_t], gf = sXg[1][m_t][n_t];
        float gg = sXg[2][m_t][n_t], go = sXg[3][m_t][n_t];
        float si = 1.f / (1.f + __expf(-gi));
        float sf = 1.f / (1.f + __expf(-gf));
        float tg = tanhf(gg);
        float so = 1.f / (1.f + __expf(-go));
        c0 = sf * c0 + si * tg;
        hn0 = so * tanhf(c0);
      }
      {
        float gi = sXg[0][m_t][16 + n_t], gf = sXg[1][m_t][16 + n_t];
        float gg = sXg[2][m_t][16 + n_t], go = sXg[3][m_t][16 + n_t];
        float si = 1.f / (1.f + __expf(-gi));
        float sf = 1.f / (1.f + __expf(-gf));
        float tg = tanhf(gg);
        float so = 1.f / (1.f + __expf(-go));
        c1 = sf * c1 + si * tg;
        hn1 = so * tanhf(c1);
      }
      {
        u16 h0 = f2bf(hn0), l0 = f2bf(hn0 - bf2f(h0));
        u16 h1 = f2bf(hn1), l1 = f2bf(hn1 - bf2f(h1));
        size_t base = (size_t)(nxt * BB + i * BT + m_t) * HH + (j << 5);
        A_ST(&g_hpak[base + n_t],      (u32)h0 | ((u32)l0 << 16));
        A_ST(&g_hpak[base + 16 + n_t], (u32)h1 | ((u32)l1 << 16));
      }

      // ---- ARRIVE: drain write-through stores, relaxed flag ----
      asm volatile("s_waitcnt vmcnt(0)" ::: "memory");
      __syncthreads();
      if (tid == 0) A_ST(myflag, (unsigned)(g + 2));
    }

    // ---- off-critical-path work in the arrive->wait window ----
    if (g >= 1023 && g < 2047) {   // y-partials of this step's h, slot g&3
      sHn[m_t][n_t] = hn0;
      sHn[m_t][16 + n_t] = hn1;
      __syncthreads();
      int fg = tid & 15, mm = tid >> 4;
      float p0 = 0, p1 = 0, p2 = 0, p3 = 0;
      for (int n = 0; n < 32; ++n) {
        float hv = sHn[mm][n];
        p0 += hv * sWo[fg * 4 + 0][n];
        p1 += hv * sWo[fg * 4 + 1][n];
        p2 += hv * sWo[fg * 4 + 2][n];
        p3 += hv * sWo[fg * 4 + 3][n];
      }
      float* pp = &g_part[(size_t)((((g & 3) * NI + i) * NJ + j) * BT + mm) * FF + fg * 4];
      A_ST(pp + 0, p0); A_ST(pp + 1, p1); A_ST(pp + 2, p2); A_ST(pp + 3, p3);
    }
    if (g >= 1025 && tid < 64) {   // emit k = g-1025 from slot (g-2)&3
      int k = g - 1025;
      int mm = tid >> 2, ff = (j << 2) + (tid & 3);
      int slot = (g - 2) & 3;
      float acc = g_bout[ff];
      for (int jj = 0; jj < NJ; ++jj)
        acc += A_LD(&g_part[(size_t)(((slot * NI + i) * NJ + jj) * BT + mm) * FF + ff]);
      size_t oidx = ((size_t)(i * BT + mm) * TT + (1023 - k)) * FF + ff;
      if (isbf) ((u16*)outv)[oidx] = f2bf(acc);
      else      ((float*)outv)[oidx] = acc;
    }

    // ---- WAIT: wave 0 polls the 16 group flags ----
    if (run) {
      if (tid < 64) {
        unsigned* fp = flags + (lane & 15) * 16;
        unsigned target = (unsigned)(g + 2);
        while (true) {
          unsigned v = A_LD(fp);
          if (__ballot(v >= target) == ~0ull) break;
          __builtin_amdgcn_s_sleep(1);
        }
      }
      asm volatile("" ::: "memory");
      __syncthreads();
    }

    // phase switch: reload registers with fused decoder weights
    if (g == 1023) {
#pragma unroll
      for (int kt = 0; kt < 16; ++kt) {
        const float* p0 = &g_weff[(size_t)gr0 * HH + kt * 32 + lq * 8];
        const float* p1 = &g_weff[(size_t)gr1 * HH + kt * 32 + lq * 8];
#pragma unroll
        for (int q = 0; q < 8; ++q) {
          float w = p0[q]; u16 hi = f2bf(w);
          wh0[kt][q] = (short)hi; wl0[kt][q] = (short)f2bf(w - bf2f(hi));
          w = p1[q]; hi = f2bf(w);
          wh1[kt][q] = (short)hi; wl1[kt][q] = (short)f2bf(w - bf2f(hi));
        }
      }
      bias0 = g_beff[gr0];
      bias1 = g_beff[gr1];
      c0 = c1 = 0.f;
    }
  }
}

extern "C" void kernel_launch(void* const* d_in, const int* in_sizes, int n_in,
                              void* d_out, int out_size, void* d_ws, size_t ws_size,
                              hipStream_t stream) {
  unsigned* bar = (unsigned*)d_ws;   // 8 groups x 16 flags, each on its own 64B line
  (void)hipMemsetAsync(bar, 0, 8192, stream);

  sniff_kernel<<<1, 64, 0, stream>>>(d_in[9]);  // w_out

  const int sizes[11] = { BB * TT * FF, G4 * FF, G4 * HH, G4, G4,
                          G4 * FF, G4 * HH, G4, G4, FF * HH, FF };
  for (int k = 0; k < 11; ++k)
    convert_kernel<<<(sizes[k] + 255) / 256, 256, 0, stream>>>(d_in[k], k, sizes[k]);

  prep_kernel<<<(G4 * HH) / 256, 256, 0, stream>>>();

  lstm_persist<<<NBLK, 256, 0, stream>>>(bar, d_out);
}

// Round 8
// 14623.495 us; speedup vs baseline: 1.4427x; 1.4427x over previous
//
#include <hip/hip_runtime.h>
#include <math.h>

#define BB 128
#define TT 1024
#define FF 64
#define HH 512
#define G4 2048            // 4*HH gate rows
#define NI 8               // batch groups (independent)
#define NJ 32              // hidden slices per group (16 units each)
#define BT 16
#define NBLK 256
#define LDK 520            // padded LDS row (u16): 1040B stride
#define SENT 0xFFFFFFFFu   // impossible packed h (hi = bf16 NaN)

typedef float f32x4 __attribute__((ext_vector_type(4)));
typedef short s16x8 __attribute__((ext_vector_type(8)));
typedef unsigned short u16;
typedef unsigned int u32;
typedef unsigned long long u64;

// ---- canonical fp32 inputs ----
__device__ float g_ts[BB * TT * FF];
__device__ float g_wihe[G4 * FF];
__device__ float g_whhe[G4 * HH];
__device__ float g_bihe[G4], g_bhhe[G4], g_bihd[G4], g_bhhd[G4];
__device__ float g_wihd[G4 * FF];
__device__ float g_whhd[G4 * HH];
__device__ float g_wout[FF * HH];
__device__ float g_bout[FF];
// ---- precomputed fused decoder weights ----
__device__ float g_weff[G4 * HH];
__device__ float g_beff[G4];
// ---- inter-block state (agent-scope atomics only; h self-flags via SENT) ----
__device__ __align__(16) u32 g_hpak[4 * BB * HH];       // 4-slot ring, packed hi|lo<<16
__device__ float g_part[4 * NI * NJ * BT * FF];         // depth-4 ring
__device__ int   g_isbf16;

__device__ __forceinline__ float bf2f(u16 u) {
  union { unsigned u; float f; } x; x.u = ((unsigned)u) << 16; return x.f;
}
__device__ __forceinline__ u16 f2bf(float f) {
  union { float f; unsigned u; } x; x.f = f;
  unsigned r = x.u + 0x7fffu + ((x.u >> 16) & 1u);
  return (u16)(r >> 16);
}

__global__ void sniff_kernel(const void* wout) {
  __shared__ int cnt[64];
  int t = threadIdx.x;
  const unsigned* d = (const unsigned*)wout;
  int c = 0;
  for (int k = t; k < 1024; k += 64) {
    unsigned b = (d[k] >> 8) & 0x7fu;
    c += (b >= 0x30u && b <= 0x3eu) ? 1 : 0;
  }
  cnt[t] = c;
  __syncthreads();
  if (t == 0) {
    int s = 0;
    for (int k = 0; k < 64; ++k) s += cnt[k];
    g_isbf16 = (s > 512) ? 1 : 0;
  }
}

__global__ void convert_kernel(const void* __restrict__ src, int which, int n) {
  int idx = blockIdx.x * 256 + threadIdx.x;
  if (idx >= n) return;
  float v;
  if (g_isbf16) v = bf2f(((const u16*)src)[idx]);
  else          v = ((const float*)src)[idx];
  float* dst;
  switch (which) {
    case 0: dst = g_ts;   break;
    case 1: dst = g_wihe; break;
    case 2: dst = g_whhe; break;
    case 3: dst = g_bihe; break;
    case 4: dst = g_bhhe; break;
    case 5: dst = g_wihd; break;
    case 6: dst = g_whhd; break;
    case 7: dst = g_bihd; break;
    case 8: dst = g_bhhd; break;
    case 9: dst = g_wout; break;
    default: dst = g_bout; break;
  }
  dst[idx] = v;
}

__global__ void prep_kernel() {
  int idx = blockIdx.x * 256 + threadIdx.x;
  int r = idx >> 9, c = idx & 511;
  float acc = g_whhd[idx];
  const float* wr = &g_wihd[r * FF];
  for (int f = 0; f < FF; ++f) acc += wr[f] * g_wout[f * HH + c];
  g_weff[idx] = acc;
  if (idx < G4) {
    float b = g_bihd[idx] + g_bhhd[idx];
    for (int f = 0; f < FF; ++f) b += g_wihd[idx * FF + f] * g_bout[f];
    g_beff[idx] = b;
  }
}

// per-launch ring init: slot 0 = h(0)=0 (legit), slots 1-3 = sentinel.
// Kernel boundary guarantees visibility before lstm_persist starts.
__global__ void hinit_kernel() {
  int idx = blockIdx.x * 256 + threadIdx.x;   // 0 .. 4*BB*HH-1
  g_hpak[idx] = (idx < BB * HH) ? 0u : SENT;
}

#define MFMA __builtin_amdgcn_mfma_f32_16x16x32_bf16
#define A_LD(p)  __hip_atomic_load((p), __ATOMIC_RELAXED, __HIP_MEMORY_SCOPE_AGENT)
#define A_ST(p, v) __hip_atomic_store((p), (v), __ATOMIC_RELAXED, __HIP_MEMORY_SCOPE_AGENT)

__global__ __launch_bounds__(256, 1) void lstm_persist(void* __restrict__ outv) {
  __shared__ u16 sH[32 * LDK];      // rows 0-15: h_hi, rows 16-31: h_lo
  __shared__ float sXg[4][16][16];  // gate exchange i/f/g/o
  __shared__ float sHn[16][16];     // h_new f32 for y-partials
  __shared__ float sWo[64][16];     // w_out[:, 16j:16j+16]

  const int tid = threadIdx.x, bid = blockIdx.x;
  const int i = bid & 7, j = bid >> 3;      // group i ~ XCD-affine, j 0..31
  const int wv = tid >> 6, lane = tid & 63;
  const int ln15 = lane & 15, lq = lane >> 4;
  const int m_t = tid >> 4, n_t = tid & 15;
  const int gr0 = (wv << 9) + (j << 4) + ln15;
  const bool isbf = (g_isbf16 != 0);

  // ---- hidden weights -> registers (hi/lo bf16), encoder phase ----
  s16x8 wh[16], wl[16];
#pragma unroll
  for (int kt = 0; kt < 16; ++kt) {
    const float* p = &g_whhe[(size_t)gr0 * HH + kt * 32 + lq * 8];
#pragma unroll
    for (int q = 0; q < 8; ++q) {
      float w = p[q]; u16 hi = f2bf(w);
      wh[kt][q] = (short)hi; wl[kt][q] = (short)f2bf(w - bf2f(hi));
    }
  }
  s16x8 bxh0, bxh1, bxl0, bxl1;   // encoder x-weight fragments
  {
    const float* p0 = &g_wihe[(size_t)gr0 * FF + lq * 8];
#pragma unroll
    for (int q = 0; q < 8; ++q) {
      float w0 = p0[q], w1 = p0[32 + q];
      u16 h0 = f2bf(w0), h1 = f2bf(w1);
      bxh0[q] = (short)h0; bxl0[q] = (short)f2bf(w0 - bf2f(h0));
      bxh1[q] = (short)h1; bxl1[q] = (short)f2bf(w1 - bf2f(h1));
    }
  }
  for (int idx = tid; idx < 64 * 16; idx += 256) {
    int f = idx >> 4, n = idx & 15;
    sWo[f][n] = g_wout[f * HH + (j << 4) + n];
  }
  float bias = g_bihe[gr0] + g_bhhe[gr0];

  float c_st = 0.f;
  const int arow = ln15 * LDK;
  const int koff = lq * 8;
  // staging geometry: row r = tid>>4 (16 batch rows), 32 units per thread
  const int sr = tid >> 4, scb = (tid & 15) * 32;

  for (int g = 0; g <= 2048; ++g) {
    const bool run = (g < 2048);
    float hn = 0.f;

    if (run) {
      const bool enc = (g < 1024);
      // issue encoder input loads first (overlap with poll)
      s16x8 xh0 = {}, xl0 = {}, xh1 = {}, xl1 = {};
      if (enc) {
        const float* xp = &g_ts[((size_t)(i * BT + ln15) * TT + g) * FF + lq * 8];
#pragma unroll
        for (int q = 0; q < 8; ++q) {
          float x0 = xp[q], x1 = xp[32 + q];
          u16 h0 = f2bf(x0), h1 = f2bf(x1);
          xh0[q] = (short)h0; xl0[q] = (short)f2bf(x0 - bf2f(h0));
          xh1[q] = (short)h1; xl1[q] = (short)f2bf(x1 - bf2f(h1));
        }
      }

      // ---- POLL-STAGE h(g) from ring slot g&3 (data self-flags) ----
      u64 q[16];
      {
        const u64* ph = (const u64*)(g_hpak + ((size_t)((g & 3) * BB + i * BT + sr) * HH) + scb);
        while (true) {
          bool bad = false;
#pragma unroll
          for (int k = 0; k < 16; ++k) q[k] = A_LD(ph + k);
#pragma unroll
          for (int k = 0; k < 16; ++k)
            bad |= ((u32)q[k] == SENT) || ((u32)(q[k] >> 32) == SENT);
          if (!bad) break;
          __builtin_amdgcn_s_sleep(1);
        }
      }
      // unpack packed u32 -> hi/lo LDS planes (v_perm)
      {
        union Du { u32 d[4]; s16x8 v; };
#pragma unroll
        for (int k = 0; k < 4; ++k) {   // 8 units per chunk
          u32 w0 = (u32)q[4 * k + 0], w1 = (u32)(q[4 * k + 0] >> 32);
          u32 w2 = (u32)q[4 * k + 1], w3 = (u32)(q[4 * k + 1] >> 32);
          u32 w4 = (u32)q[4 * k + 2], w5 = (u32)(q[4 * k + 2] >> 32);
          u32 w6 = (u32)q[4 * k + 3], w7 = (u32)(q[4 * k + 3] >> 32);
          Du hi, lo;
          hi.d[0] = __builtin_amdgcn_perm(w1, w0, 0x05040100u);
          hi.d[1] = __builtin_amdgcn_perm(w3, w2, 0x05040100u);
          hi.d[2] = __builtin_amdgcn_perm(w5, w4, 0x05040100u);
          hi.d[3] = __builtin_amdgcn_perm(w7, w6, 0x05040100u);
          lo.d[0] = __builtin_amdgcn_perm(w1, w0, 0x07060302u);
          lo.d[1] = __builtin_amdgcn_perm(w3, w2, 0x07060302u);
          lo.d[2] = __builtin_amdgcn_perm(w5, w4, 0x07060302u);
          lo.d[3] = __builtin_amdgcn_perm(w7, w6, 0x07060302u);
          *(s16x8*)&sH[sr * LDK + scb + 8 * k] = hi.v;
          *(s16x8*)&sH[(16 + sr) * LDK + scb + 8 * k] = lo.v;
        }
      }
      __syncthreads();

      f32x4 acc0 = {bias, bias, bias, bias};
      f32x4 acc1 = {0.f, 0.f, 0.f, 0.f};
      f32x4 acc2 = {0.f, 0.f, 0.f, 0.f};
#pragma unroll
      for (int kt = 0; kt < 16; ++kt) {
        s16x8 ah = *(s16x8*)&sH[arow + kt * 32 + koff];
        s16x8 al = *(s16x8*)&sH[16 * LDK + arow + kt * 32 + koff];
        acc0 = MFMA(ah, wh[kt], acc0, 0, 0, 0);
        acc1 = MFMA(al, wh[kt], acc1, 0, 0, 0);
        acc2 = MFMA(ah, wl[kt], acc2, 0, 0, 0);
      }
      if (enc) {
        acc0 = MFMA(xh0, bxh0, acc0, 0, 0, 0);
        acc0 = MFMA(xh1, bxh1, acc0, 0, 0, 0);
        acc1 = MFMA(xl0, bxh0, acc1, 0, 0, 0);
        acc1 = MFMA(xl1, bxh1, acc1, 0, 0, 0);
        acc2 = MFMA(xh0, bxl0, acc2, 0, 0, 0);
        acc2 = MFMA(xh1, bxl1, acc2, 0, 0, 0);
      }
      sXg[wv][lq * 4 + 0][ln15] = acc0.x + acc1.x + acc2.x;
      sXg[wv][lq * 4 + 1][ln15] = acc0.y + acc1.y + acc2.y;
      sXg[wv][lq * 4 + 2][ln15] = acc0.z + acc1.z + acc2.z;
      sXg[wv][lq * 4 + 3][ln15] = acc0.w + acc1.w + acc2.w;
      __syncthreads();

      float gi = sXg[0][m_t][n_t], gf = sXg[1][m_t][n_t];
      float gg = sXg[2][m_t][n_t], go = sXg[3][m_t][n_t];
      float si = 1.f / (1.f + __expf(-gi));
      float sf = 1.f / (1.f + __expf(-gf));
      float tg = tanhf(gg);
      float so = 1.f / (1.f + __expf(-go));
      c_st = sf * c_st + si * tg;
      hn = so * tanhf(c_st);
      {
        u16 h0 = f2bf(hn), l0 = f2bf(hn - bf2f(h0));
        size_t col = (size_t)(i * BT + m_t) * HH + (j << 4) + n_t;
        // publish h(g+1) into slot (g+1)&3 (critical path: just the store)
        A_ST(&g_hpak[(size_t)(((g + 1) & 3) * BB) * HH + col], (u32)h0 | ((u32)l0 << 16));
        // re-sentinel slot (g+3)&3 for its future h(g+3) use (same thread,
        // same address as that future write -> HW-ordered; readers of the old
        // h(g-1) all finished >=1 step ago since h(g) was observed complete)
        A_ST(&g_hpak[(size_t)(((g + 3) & 3) * BB) * HH + col], SENT);
      }
    }

    // ---- off-critical-path: y-partials + emission (2-step lag) ----
    if (g >= 1023 && g < 2047) {   // partials of this step's h, slot g&3
      sHn[m_t][n_t] = hn;
      __syncthreads();
      int fg = tid & 15, mm = tid >> 4;
      float p0 = 0, p1 = 0, p2 = 0, p3 = 0;
      for (int n = 0; n < 16; ++n) {
        float hv = sHn[mm][n];
        p0 += hv * sWo[fg * 4 + 0][n];
        p1 += hv * sWo[fg * 4 + 1][n];
        p2 += hv * sWo[fg * 4 + 2][n];
        p3 += hv * sWo[fg * 4 + 3][n];
      }
      float* pp = &g_part[(size_t)((((g & 3) * NI + i) * NJ + j) * BT + mm) * FF + fg * 4];
      A_ST(pp + 0, p0); A_ST(pp + 1, p1); A_ST(pp + 2, p2); A_ST(pp + 3, p3);
      // drain so partials are retired strictly before the NEXT h publication;
      // readers lag 2 full steps behind.
      asm volatile("s_waitcnt vmcnt(0)" ::: "memory");
    }
    if (g >= 1025 && j < 16 && tid < 64) {   // emit k = g-1025 from slot (g-2)&3
      int k = g - 1025;
      int mm = tid >> 2, ff = (j << 2) + (tid & 3);
      int slot = (g - 2) & 3;
      float acc = g_bout[ff];
      for (int jj = 0; jj < NJ; ++jj)
        acc += A_LD(&g_part[(size_t)(((slot * NI + i) * NJ + jj) * BT + mm) * FF + ff]);
      size_t oidx = ((size_t)(i * BT + mm) * TT + (1023 - k)) * FF + ff;
      if (isbf) ((u16*)outv)[oidx] = f2bf(acc);
      else      ((float*)outv)[oidx] = acc;
    }

    // phase switch: reload registers with fused decoder weights
    if (g == 1023) {
#pragma unroll
      for (int kt = 0; kt < 16; ++kt) {
        const float* p = &g_weff[(size_t)gr0 * HH + kt * 32 + lq * 8];
#pragma unroll
        for (int q = 0; q < 8; ++q) {
          float w = p[q]; u16 hi = f2bf(w);
          wh[kt][q] = (short)hi; wl[kt][q] = (short)f2bf(w - bf2f(hi));
        }
      }
      bias = g_beff[gr0];
      c_st = 0.f;
    }
  }
}

extern "C" void kernel_launch(void* const* d_in, const int* in_sizes, int n_in,
                              void* d_out, int out_size, void* d_ws, size_t ws_size,
                              hipStream_t stream) {
  sniff_kernel<<<1, 64, 0, stream>>>(d_in[9]);  // w_out

  const int sizes[11] = { BB * TT * FF, G4 * FF, G4 * HH, G4, G4,
                          G4 * FF, G4 * HH, G4, G4, FF * HH, FF };
  for (int k = 0; k < 11; ++k)
    convert_kernel<<<(sizes[k] + 255) / 256, 256, 0, stream>>>(d_in[k], k, sizes[k]);

  prep_kernel<<<(G4 * HH) / 256, 256, 0, stream>>>();
  hinit_kernel<<<(4 * BB * HH) / 256, 256, 0, stream>>>();

  lstm_persist<<<NBLK, 256, 0, stream>>>(d_out);
}